// Round 1
// baseline (12942.445 us; speedup 1.0000x reference)
//
#include <hip/hip_runtime.h>

// MI-LSTM on MI355X (gfx950). I/O is FP32 (per reference dtypes); compute
// uses bf16 MFMA internally (test tolerance is bf16-grade: 1.156e-2).
// B=128, T=256, D_IN=1024, UNITS=1024, N_CLASS=1024.
//
// R6 change: the 256 per-step milstm_step launches are replaced by persistent
// per-chunk kernels (cooperative launch, custom device-scope barrier per step).
// WrT slice (32 KB) stays in LDS for all 32 steps of a chunk; c-state lives in
// registers across the chunk; XP prefetched per step. Removes per-step launch
// overhead, per-step WrT re-staging (2 GB total), and 2 MB/step of c traffic.

typedef unsigned short u16;
typedef __attribute__((ext_vector_type(8))) short short8;   // 8 x bf16 (4 VGPRs)
typedef __attribute__((ext_vector_type(4))) float f32x4;    // MFMA accumulator

#define B_SZ   128
#define T_SZ   256
#define D_IN   1024
#define UNITS  1024
#define FOURU  4096

__device__ __forceinline__ float bf2f(u16 h) {
    return __uint_as_float(((unsigned int)h) << 16);
}
__device__ __forceinline__ u16 f2bf(float f) {
    unsigned int u = __float_as_uint(f);
    u += 0x7fffu + ((u >> 16) & 1u);   // round-to-nearest-even
    return (u16)(u >> 16);
}
__device__ __forceinline__ float sigmoidf_(float x) {
    return 1.0f / (1.0f + __expf(-x));
}

// ---------------------------------------------------------------- transpose+cvt
// out[n][k] = bf16(in[k][n]);  in is fp32 [K][N] row-major.
__global__ __launch_bounds__(256) void transpose_cvt(
    const float* __restrict__ in, u16* __restrict__ out, int K, int N)
{
    __shared__ u16 t[32][33];
    int n0 = blockIdx.x * 32, k0 = blockIdx.y * 32;
    int c = threadIdx.x & 31, r = threadIdx.x >> 5;   // r in 0..7
    #pragma unroll
    for (int i = 0; i < 4; ++i) {
        int kk = r + i * 8;
        t[kk][c] = f2bf(in[(size_t)(k0 + kk) * N + n0 + c]);
    }
    __syncthreads();
    #pragma unroll
    for (int i = 0; i < 4; ++i) {
        int nn = r + i * 8;
        out[(size_t)(n0 + nn) * K + k0 + c] = t[c][nn];
    }
}

// ---------------------------------------------------------------- XP GEMM (one time-chunk)
// Cc[b*tc+tt][n] = bf16( x[b][t0+tt][:] @ Wk + bk ),  tt in [0,tc).
__global__ __launch_bounds__(256) void gemm_xp_chunk(
    const float* __restrict__ X, const u16* __restrict__ Bt,
    const float* __restrict__ bias, u16* __restrict__ Cc,
    int t0, int tcShift)
{
    __shared__ __align__(16) u16 As[128 * 40];
    __shared__ __align__(16) u16 Bs[128 * 40];
    int tid = threadIdx.x;
    int wave = tid >> 6, lane = tid & 63;
    int bm = blockIdx.x * 128;     // row' base, row' = b*tc + tt
    int bn = blockIdx.y * 128;
    int wm = (wave & 1) * 64, wn = (wave >> 1) * 64;
    int lm = lane & 15, lq = lane >> 4;
    int tcMask = (1 << tcShift) - 1;

    f32x4 acc[4][4] = {};

    for (int k0 = 0; k0 < D_IN; k0 += 32) {
        #pragma unroll
        for (int i = 0; i < 2; ++i) {
            int idx = tid + i * 256;
            int r = idx >> 2, q = idx & 3;
            int rowp = bm + r;
            int b = rowp >> tcShift;
            int tt = rowp & tcMask;
            const float* xs = &X[(size_t)(b * T_SZ + t0 + tt) * D_IN + k0 + q * 8];
            float4 f0 = *(const float4*)xs;
            float4 f1 = *(const float4*)(xs + 4);
            uint4 v;
            v.x = (unsigned)f2bf(f0.x) | ((unsigned)f2bf(f0.y) << 16);
            v.y = (unsigned)f2bf(f0.z) | ((unsigned)f2bf(f0.w) << 16);
            v.z = (unsigned)f2bf(f1.x) | ((unsigned)f2bf(f1.y) << 16);
            v.w = (unsigned)f2bf(f1.z) | ((unsigned)f2bf(f1.w) << 16);
            *(uint4*)&As[r * 40 + q * 8] = v;
            *(uint4*)&Bs[r * 40 + q * 8] =
                *(const uint4*)&Bt[(size_t)(bn + r) * D_IN + k0 + q * 8];
        }
        __syncthreads();
        short8 af[4], bf[4];
        #pragma unroll
        for (int t = 0; t < 4; ++t) {
            af[t] = *(const short8*)&As[(wm + t * 16 + lm) * 40 + lq * 8];
            bf[t] = *(const short8*)&Bs[(wn + t * 16 + lm) * 40 + lq * 8];
        }
        #pragma unroll
        for (int mt = 0; mt < 4; ++mt)
            #pragma unroll
            for (int nt = 0; nt < 4; ++nt)
                acc[mt][nt] = __builtin_amdgcn_mfma_f32_16x16x32_bf16(
                    af[mt], bf[nt], acc[mt][nt], 0, 0, 0);
        __syncthreads();
    }

    #pragma unroll
    for (int mt = 0; mt < 4; ++mt) {
        #pragma unroll
        for (int nt = 0; nt < 4; ++nt) {
            int col = bn + wn + nt * 16 + lm;
            float bv = bias[col];
            #pragma unroll
            for (int r = 0; r < 4; ++r) {
                int rowp = bm + wm + mt * 16 + lq * 4 + r;
                Cc[(size_t)rowp * FOURU + col] = f2bf(acc[mt][nt][r] + bv);
            }
        }
    }
}

// ---------------------------------------------------------------- persistent LSTM chunk (R6)
// 256 blocks x 256 threads, one block/CU, runs tc steps with a device-scope
// barrier between steps. Block owns u0=blockIdx*4: 4 u-cols x 4 gates = 16
// n-cols, M = all 128 rows. WrT slice (16x1024 bf16) staged to LDS ONCE per
// chunk; h streamed from global (L2-hot); c held in registers across steps.
__global__ __launch_bounds__(256) void milstm_chunk(
    const u16* __restrict__ XPc,     // bf16 [128*tc][4096], rowp = b*tc + s
    const u16* __restrict__ WrT,     // [4096][1024] bf16
    const float* __restrict__ br,
    const float* __restrict__ alpha,
    const float* __restrict__ beta1,
    const float* __restrict__ beta2,
    const u16* __restrict__ h0bf,    // [128][1024] bf16 (initial state)
    u16* __restrict__ hb0,
    u16* __restrict__ hb1,
    float* __restrict__ cbuf,        // [128][1024] f32 (chunk in/out of c-state)
    unsigned* __restrict__ bar,      // monotonic barrier counter (zeroed at t=0)
    int t0, int tc)
{
    __shared__ __align__(16) u16 WrS[16 * 1032];   // +8 pad: 2-way banks only
    __shared__ float zbuf[16][132];                // [n-local][m] hp partials
    __shared__ float brS[16], alS[16], b1S[16], b2S[16];

    int tid = threadIdx.x;
    int wave = tid >> 6, lane = tid & 63;
    int lm = lane & 15, lq = lane >> 4;
    int u0 = blockIdx.x * 4;

    // stage WrT slice once per chunk: 16 rows x 1024 bf16 = 2048 uint4
    #pragma unroll
    for (int i = 0; i < 8; ++i) {
        int idx = i * 256 + tid;
        int l = idx >> 7, q = idx & 127;
        int n = ((l >> 2) << 10) + u0 + (l & 3);
        *(uint4*)&WrS[l * 1032 + q * 8] = *(const uint4*)&WrT[(size_t)n * 1024 + q * 8];
    }
    if (tid < 16) {
        int n = ((tid >> 2) << 10) + u0 + (tid & 3);
        brS[tid] = br[n]; alS[tid] = alpha[n];
        b1S[tid] = beta1[n]; b2S[tid] = beta2[n];
    }

    // c-state into registers: thread owns (row=item>>2, col=u0+(item&3)), e=0,1
    float cv[2];
    size_t gidx[2];
    #pragma unroll
    for (int e = 0; e < 2; ++e) {
        int item = tid + e * 256;
        int row = item >> 2, j = item & 3;
        gidx[e] = (size_t)row * UNITS + u0 + j;
        cv[e] = cbuf[gidx[e]];
    }
    __syncthreads();

    for (int s = 0; s < tc; ++s) {
        int t = t0 + s;
        const u16* hsrc = (t == 0) ? h0bf : ((t & 1) ? hb0 : hb1);
        u16* hdst = (t & 1) ? hb1 : hb0;

        // prefetch this step's XP values (epilogue operands) early; their L3
        // latency hides under the K-loop MFMAs.
        float xpv[2][4];
        #pragma unroll
        for (int e = 0; e < 2; ++e) {
            int item = tid + e * 256;
            int row = item >> 2, j = item & 3;
            #pragma unroll
            for (int g = 0; g < 4; ++g)
                xpv[e][g] = bf2f(XPc[(size_t)(row * tc + s) * FOURU + ((g << 10) + u0 + j)]);
        }

        // hp = h @ Wr-slice: wave handles m-tiles {wave, wave+4}
        const u16* A0 = &hsrc[(size_t)(wave * 16 + lm) * UNITS];
        const u16* A1 = &hsrc[(size_t)((wave + 4) * 16 + lm) * UNITS];
        const u16* Bl = &WrS[lm * 1032];
        f32x4 acc0 = {}, acc1 = {};
        #pragma unroll 8
        for (int k0 = 0; k0 < UNITS; k0 += 32) {
            short8 b  = *(const short8*)&Bl[k0 + lq * 8];
            short8 a0 = *(const short8*)&A0[k0 + lq * 8];
            short8 a1 = *(const short8*)&A1[k0 + lq * 8];
            acc0 = __builtin_amdgcn_mfma_f32_16x16x32_bf16(a0, b, acc0, 0, 0, 0);
            acc1 = __builtin_amdgcn_mfma_f32_16x16x32_bf16(a1, b, acc1, 0, 0, 0);
        }
        #pragma unroll
        for (int r = 0; r < 4; ++r) {
            zbuf[lm][wave * 16 + lq * 4 + r]       = acc0[r];
            zbuf[lm][(wave + 4) * 16 + lq * 4 + r] = acc1[r];
        }
        __syncthreads();

        // fused MI gates: 512 items = 128 rows x 4 u-cols
        #pragma unroll
        for (int e = 0; e < 2; ++e) {
            int item = tid + e * 256;
            int row = item >> 2, j = item & 3;
            float z[4];
            #pragma unroll
            for (int g = 0; g < 4; ++g) {
                int l = g * 4 + j;
                float hp = zbuf[l][row] + brS[l];
                float xp = xpv[e][g];
                z[g] = alS[l] * xp * hp + b1S[l] * xp + b2S[l] * hp;
            }
            float cn = tanhf(z[2]) * sigmoidf_(z[0]) + cv[e] * sigmoidf_(z[1]);
            cv[e] = cn;
            hdst[gidx[e]] = f2bf(tanhf(cn) * sigmoidf_(z[3]));
        }

        // device-scope barrier between steps (grid.sync structure):
        // release all h stores, block barrier, leader arrive+acquire-spin.
        __threadfence();
        __syncthreads();
        if (tid == 0) {
            __hip_atomic_fetch_add(bar, 1u, __ATOMIC_RELEASE, __HIP_MEMORY_SCOPE_AGENT);
            unsigned tgt = 256u * (unsigned)(t + 1);
            while (__hip_atomic_load(bar, __ATOMIC_ACQUIRE, __HIP_MEMORY_SCOPE_AGENT) < tgt)
                __builtin_amdgcn_s_sleep(2);
        }
        __syncthreads();
    }

    // write c-state back once per chunk
    #pragma unroll
    for (int e = 0; e < 2; ++e)
        cbuf[gidx[e]] = cv[e];
}

// ---------------------------------------------------------------- final GEMM
// out[128][1024] = h @ Wc + bc (fp32 out); WcT bf16 [1024][1024].
__global__ __launch_bounds__(256) void gemm_out(
    const u16* __restrict__ h, const u16* __restrict__ WcT,
    const float* __restrict__ bc, float* __restrict__ out)
{
    int tid = threadIdx.x;
    int wave = tid >> 6, lane = tid & 63;
    int bx = blockIdx.x;               // 128 blocks: 8 row-tiles x 16 col-grps
    int row0 = (bx & 7) * 16;
    int n0 = (bx >> 3) * 64 + wave * 16;
    int lm = lane & 15, lq = lane >> 4;

    f32x4 acc = {};
    const u16* Arow = &h[(size_t)(row0 + lm) * UNITS];
    const u16* Brow = &WcT[(size_t)(n0 + lm) * UNITS];
    #pragma unroll 8
    for (int k0 = 0; k0 < UNITS; k0 += 32) {
        short8 a = *(const short8*)&Arow[k0 + lq * 8];
        short8 b = *(const short8*)&Brow[k0 + lq * 8];
        acc = __builtin_amdgcn_mfma_f32_16x16x32_bf16(a, b, acc, 0, 0, 0);
    }
    int col = n0 + lm;
    float bv = bc[col];
    #pragma unroll
    for (int r = 0; r < 4; ++r) {
        int row = row0 + lq * 4 + r;
        out[(size_t)row * 1024 + col] = acc[r] + bv;
    }
}

// ---------------------------------------------------------------- utilities
__global__ void cvt_f32_bf16(const float* __restrict__ in, u16* __restrict__ out, int n) {
    int i = blockIdx.x * 256 + threadIdx.x;
    if (i < n) out[i] = f2bf(in[i]);
}
__global__ void cvt_bf16_f32(const u16* __restrict__ in, float* __restrict__ out, int n) {
    int i = blockIdx.x * 256 + threadIdx.x;
    if (i < n) out[i] = bf2f(in[i]);
}
__global__ void copy_f32(const float* __restrict__ in, float* __restrict__ out, int n) {
    int i = blockIdx.x * 256 + threadIdx.x;
    if (i < n) out[i] = in[i];
}
__global__ void zero_u32(unsigned* __restrict__ p, int n) {
    int i = threadIdx.x;
    if (i < n) p[i] = 0u;
}

// ---------------------------------------------------------------- launch
extern "C" void kernel_launch(void* const* d_in, const int* in_sizes, int n_in,
                              void* d_out, int out_size, void* d_ws, size_t ws_size,
                              hipStream_t stream)
{
    const float* x     = (const float*)d_in[0];   // [128,256,1024]
    const float* h0    = (const float*)d_in[1];   // [128,1024]
    const float* c0    = (const float*)d_in[2];   // [128,1024]
    const float* Wk    = (const float*)d_in[3];   // [1024,4096]
    const float* bk    = (const float*)d_in[4];   // [4096]
    const float* Wr    = (const float*)d_in[5];   // [1024,4096]
    const float* br    = (const float*)d_in[6];   // [4096]
    const float* alpha = (const float*)d_in[7];   // [1,4096]
    const float* beta1 = (const float*)d_in[8];   // [1,4096]
    const float* beta2 = (const float*)d_in[9];   // [1,4096]
    const float* Wc    = (const float*)d_in[10];  // [1024,1024]
    const float* bc    = (const float*)d_in[11];  // [1024]
    float* out = (float*)d_out;                   // out|h|c, each 128*1024 fp32

    // ws layout: small state, barrier counters, bf16 weights, then XP chunk
    char* p = (char*)d_ws;
    u16* h0bf = (u16*)p;  p += (size_t)B_SZ * UNITS * 2;
    u16* hb0  = (u16*)p;  p += (size_t)B_SZ * UNITS * 2;
    u16* hb1  = (u16*)p;  p += (size_t)B_SZ * UNITS * 2;
    float* cbuf = (float*)p; p += (size_t)B_SZ * UNITS * 4;
    unsigned* bar = (unsigned*)p; p += 256;       // barrier counters (16B-aligned)
    u16* WkT = (u16*)p;   p += (size_t)FOURU * D_IN * 2;
    u16* WrT = (u16*)p;   p += (size_t)FOURU * UNITS * 2;
    u16* WcT = (u16*)p;   p += (size_t)1024 * 1024 * 2;
    u16* XPc = (u16*)p;   // bf16 [B_SZ*tc][4096]

    size_t fixedB = (size_t)(p - (char*)d_ws);
    int tc = 32, tcShift = 5;
    while (tc > 1 && fixedB + (size_t)B_SZ * tc * FOURU * 2 > ws_size) {
        tc >>= 1; tcShift -= 1;
    }

    // 1) weight transposes + fp32->bf16 convert
    transpose_cvt<<<dim3(FOURU / 32, D_IN / 32), 256, 0, stream>>>(Wk, WkT, D_IN, FOURU);
    transpose_cvt<<<dim3(FOURU / 32, UNITS / 32), 256, 0, stream>>>(Wr, WrT, UNITS, FOURU);
    transpose_cvt<<<dim3(1024 / 32, 1024 / 32), 256, 0, stream>>>(Wc, WcT, 1024, 1024);

    // 2) state init: h0 -> bf16, c0 -> fp32 scratch, barrier counters -> 0
    cvt_f32_bf16<<<(B_SZ * UNITS) / 256, 256, 0, stream>>>(h0, h0bf, B_SZ * UNITS);
    copy_f32<<<(B_SZ * UNITS) / 256, 256, 0, stream>>>(c0, cbuf, B_SZ * UNITS);
    zero_u32<<<1, 64, 0, stream>>>(bar, 64);

    // 3) recurrence: per chunk, XP GEMM then one persistent cooperative kernel
    for (int t0 = 0; t0 < T_SZ; t0 += tc) {
        gemm_xp_chunk<<<dim3(tc, FOURU / 128), 256, 0, stream>>>(
            x, WkT, bk, XPc, t0, tcShift);
        void* args[] = { (void*)&XPc, (void*)&WrT, (void*)&br, (void*)&alpha,
                         (void*)&beta1, (void*)&beta2, (void*)&h0bf, (void*)&hb0,
                         (void*)&hb1, (void*)&cbuf, (void*)&bar, (void*)&t0,
                         (void*)&tc };
        hipError_t err = hipLaunchCooperativeKernel(
            (const void*)milstm_chunk, dim3(256), dim3(256), args, 0, stream);
        if (err != hipSuccess) {
            // fallback: kernel uses only custom barriers; 256 blocks at
            // 1 block/CU are co-resident on 256 CUs with a plain launch.
            milstm_chunk<<<256, 256, 0, stream>>>(
                XPc, WrT, br, alpha, beta1, beta2, h0bf, hb0, hb1, cbuf, bar, t0, tc);
        }
    }
    // T=256 even -> final h in hb1

    // 4) out = h @ Wc + bc ; emit h (bf16->f32), c (f32)
    gemm_out<<<128, 256, 0, stream>>>(hb1, WcT, bc, out);
    cvt_bf16_f32<<<(B_SZ * UNITS) / 256, 256, 0, stream>>>(hb1, out + B_SZ * UNITS, B_SZ * UNITS);
    copy_f32<<<(B_SZ * UNITS) / 256, 256, 0, stream>>>(cbuf, out + 2 * B_SZ * UNITS, B_SZ * UNITS);
}

// Round 2
// 5006.794 us; speedup vs baseline: 2.5850x; 2.5850x over previous
//
#include <hip/hip_runtime.h>

// MI-LSTM on MI355X (gfx950). I/O is FP32 (per reference dtypes); compute
// uses bf16 MFMA internally (test tolerance is bf16-grade: 1.156e-2).
// B=128, T=256, D_IN=1024, UNITS=1024, N_CLASS=1024.
//
// R7 change: fix the R6 persistent-kernel barrier. R6 spent 47 us/step in
// cache-maintenance storms: per-THREAD __threadfence() (1024 L2-writebacks
// per step) and ACQUIRE spin polls (L2-invalidate every ~200ns from 256 CUs).
// Now: one release-fence (wbl2) per block after syncthreads, two-level
// RELAXED arrive (8 sub-counters -> root), RELAXED spin, one acquire-fence
// (inv) per block after spin exit. Next-step XP prefetched before the
// barrier so its L3 latency hides under the spin. Plain launch (256 blocks,
// capacity >= 2 blocks/CU => all resident; no cooperative API needed).

typedef unsigned short u16;
typedef __attribute__((ext_vector_type(8))) short short8;   // 8 x bf16 (4 VGPRs)
typedef __attribute__((ext_vector_type(4))) float f32x4;    // MFMA accumulator

#define B_SZ   128
#define T_SZ   256
#define D_IN   1024
#define UNITS  1024
#define FOURU  4096

__device__ __forceinline__ float bf2f(u16 h) {
    return __uint_as_float(((unsigned int)h) << 16);
}
__device__ __forceinline__ u16 f2bf(float f) {
    unsigned int u = __float_as_uint(f);
    u += 0x7fffu + ((u >> 16) & 1u);   // round-to-nearest-even
    return (u16)(u >> 16);
}
__device__ __forceinline__ float sigmoidf_(float x) {
    return 1.0f / (1.0f + __expf(-x));
}

// ---------------------------------------------------------------- transpose+cvt
// out[n][k] = bf16(in[k][n]);  in is fp32 [K][N] row-major.
__global__ __launch_bounds__(256) void transpose_cvt(
    const float* __restrict__ in, u16* __restrict__ out, int K, int N)
{
    __shared__ u16 t[32][33];
    int n0 = blockIdx.x * 32, k0 = blockIdx.y * 32;
    int c = threadIdx.x & 31, r = threadIdx.x >> 5;   // r in 0..7
    #pragma unroll
    for (int i = 0; i < 4; ++i) {
        int kk = r + i * 8;
        t[kk][c] = f2bf(in[(size_t)(k0 + kk) * N + n0 + c]);
    }
    __syncthreads();
    #pragma unroll
    for (int i = 0; i < 4; ++i) {
        int nn = r + i * 8;
        out[(size_t)(n0 + nn) * K + k0 + c] = t[c][nn];
    }
}

// ---------------------------------------------------------------- XP GEMM (one time-chunk)
// Cc[b*tc+tt][n] = bf16( x[b][t0+tt][:] @ Wk + bk ),  tt in [0,tc).
__global__ __launch_bounds__(256) void gemm_xp_chunk(
    const float* __restrict__ X, const u16* __restrict__ Bt,
    const float* __restrict__ bias, u16* __restrict__ Cc,
    int t0, int tcShift)
{
    __shared__ __align__(16) u16 As[128 * 40];
    __shared__ __align__(16) u16 Bs[128 * 40];
    int tid = threadIdx.x;
    int wave = tid >> 6, lane = tid & 63;
    int bm = blockIdx.x * 128;     // row' base, row' = b*tc + tt
    int bn = blockIdx.y * 128;
    int wm = (wave & 1) * 64, wn = (wave >> 1) * 64;
    int lm = lane & 15, lq = lane >> 4;
    int tcMask = (1 << tcShift) - 1;

    f32x4 acc[4][4] = {};

    for (int k0 = 0; k0 < D_IN; k0 += 32) {
        #pragma unroll
        for (int i = 0; i < 2; ++i) {
            int idx = tid + i * 256;
            int r = idx >> 2, q = idx & 3;
            int rowp = bm + r;
            int b = rowp >> tcShift;
            int tt = rowp & tcMask;
            const float* xs = &X[(size_t)(b * T_SZ + t0 + tt) * D_IN + k0 + q * 8];
            float4 f0 = *(const float4*)xs;
            float4 f1 = *(const float4*)(xs + 4);
            uint4 v;
            v.x = (unsigned)f2bf(f0.x) | ((unsigned)f2bf(f0.y) << 16);
            v.y = (unsigned)f2bf(f0.z) | ((unsigned)f2bf(f0.w) << 16);
            v.z = (unsigned)f2bf(f1.x) | ((unsigned)f2bf(f1.y) << 16);
            v.w = (unsigned)f2bf(f1.z) | ((unsigned)f2bf(f1.w) << 16);
            *(uint4*)&As[r * 40 + q * 8] = v;
            *(uint4*)&Bs[r * 40 + q * 8] =
                *(const uint4*)&Bt[(size_t)(bn + r) * D_IN + k0 + q * 8];
        }
        __syncthreads();
        short8 af[4], bf[4];
        #pragma unroll
        for (int t = 0; t < 4; ++t) {
            af[t] = *(const short8*)&As[(wm + t * 16 + lm) * 40 + lq * 8];
            bf[t] = *(const short8*)&Bs[(wn + t * 16 + lm) * 40 + lq * 8];
        }
        #pragma unroll
        for (int mt = 0; mt < 4; ++mt)
            #pragma unroll
            for (int nt = 0; nt < 4; ++nt)
                acc[mt][nt] = __builtin_amdgcn_mfma_f32_16x16x32_bf16(
                    af[mt], bf[nt], acc[mt][nt], 0, 0, 0);
        __syncthreads();
    }

    #pragma unroll
    for (int mt = 0; mt < 4; ++mt) {
        #pragma unroll
        for (int nt = 0; nt < 4; ++nt) {
            int col = bn + wn + nt * 16 + lm;
            float bv = bias[col];
            #pragma unroll
            for (int r = 0; r < 4; ++r) {
                int rowp = bm + wm + mt * 16 + lq * 4 + r;
                Cc[(size_t)rowp * FOURU + col] = f2bf(acc[mt][nt][r] + bv);
            }
        }
    }
}

// ---------------------------------------------------------------- persistent LSTM chunk (R7)
// 256 blocks x 256 threads, one block/CU, runs tc steps with a device-scope
// barrier between steps. Block owns u0=blockIdx*4: 4 u-cols x 4 gates = 16
// n-cols, M = all 128 rows. WrT slice (16x1024 bf16) staged to LDS ONCE per
// chunk; h streamed from global (L2/L3); c held in registers across steps.
//
// Barrier layout in bar[]: sub-counter g at bar[g*32] (g = blockIdx&7, 128B
// apart), root at bar[256]. Monotonic across the whole sequence; zeroed once
// per replay. Hardware chain: release-fence (wbl2, vmcnt-waited) precedes the
// relaxed arrive-add, so spin-exit on root implies all 256 L2-writebacks are
// complete; one acquire-fence (inv) then makes L3's fresh h visible.
__global__ __launch_bounds__(256) void milstm_chunk(
    const u16* __restrict__ XPc,     // bf16 [128*tc][4096], rowp = b*tc + s
    const u16* __restrict__ WrT,     // [4096][1024] bf16
    const float* __restrict__ br,
    const float* __restrict__ alpha,
    const float* __restrict__ beta1,
    const float* __restrict__ beta2,
    const u16* __restrict__ h0bf,    // [128][1024] bf16 (initial state)
    u16* __restrict__ hb0,
    u16* __restrict__ hb1,
    float* __restrict__ cbuf,        // [128][1024] f32 (chunk in/out of c-state)
    unsigned* __restrict__ bar,      // barrier counters (zeroed at t=0)
    int t0, int tc)
{
    __shared__ __align__(16) u16 WrS[16 * 1032];   // +8 pad: 2-way banks only
    __shared__ float zbuf[16][132];                // [n-local][m] hp partials
    __shared__ float brS[16], alS[16], b1S[16], b2S[16];

    int tid = threadIdx.x;
    int wave = tid >> 6, lane = tid & 63;
    int lm = lane & 15, lq = lane >> 4;
    int u0 = blockIdx.x * 4;

    // stage WrT slice once per chunk: 16 rows x 1024 bf16 = 2048 uint4
    #pragma unroll
    for (int i = 0; i < 8; ++i) {
        int idx = i * 256 + tid;
        int l = idx >> 7, q = idx & 127;
        int n = ((l >> 2) << 10) + u0 + (l & 3);
        *(uint4*)&WrS[l * 1032 + q * 8] = *(const uint4*)&WrT[(size_t)n * 1024 + q * 8];
    }
    if (tid < 16) {
        int n = ((tid >> 2) << 10) + u0 + (tid & 3);
        brS[tid] = br[n]; alS[tid] = alpha[n];
        b1S[tid] = beta1[n]; b2S[tid] = beta2[n];
    }

    // c-state into registers: thread owns (row=item>>2, col=u0+(item&3)), e=0,1
    float cv[2];
    size_t gidx[2];
    int xrow[2], xj[2];
    #pragma unroll
    for (int e = 0; e < 2; ++e) {
        int item = tid + e * 256;
        int row = item >> 2, j = item & 3;
        xrow[e] = row; xj[e] = j;
        gidx[e] = (size_t)row * UNITS + u0 + j;
        cv[e] = cbuf[gidx[e]];
    }
    __syncthreads();

    // prefetch XP for s = 0 (epilogue operands; latency hides under K-loop)
    float xpv[2][4];
    #pragma unroll
    for (int e = 0; e < 2; ++e)
        #pragma unroll
        for (int g = 0; g < 4; ++g)
            xpv[e][g] = bf2f(XPc[(size_t)(xrow[e] * tc + 0) * FOURU + ((g << 10) + u0 + xj[e])]);

    unsigned sgrp = (blockIdx.x & 7) * 32;   // sub-counter index

    for (int s = 0; s < tc; ++s) {
        int t = t0 + s;
        const u16* hsrc = (t == 0) ? h0bf : ((t & 1) ? hb0 : hb1);
        u16* hdst = (t & 1) ? hb1 : hb0;

        // hp = h @ Wr-slice: wave handles m-tiles {wave, wave+4}
        const u16* A0 = &hsrc[(size_t)(wave * 16 + lm) * UNITS];
        const u16* A1 = &hsrc[(size_t)((wave + 4) * 16 + lm) * UNITS];
        const u16* Bl = &WrS[lm * 1032];
        f32x4 acc0 = {}, acc1 = {};
        #pragma unroll 8
        for (int k0 = 0; k0 < UNITS; k0 += 32) {
            short8 b  = *(const short8*)&Bl[k0 + lq * 8];
            short8 a0 = *(const short8*)&A0[k0 + lq * 8];
            short8 a1 = *(const short8*)&A1[k0 + lq * 8];
            acc0 = __builtin_amdgcn_mfma_f32_16x16x32_bf16(a0, b, acc0, 0, 0, 0);
            acc1 = __builtin_amdgcn_mfma_f32_16x16x32_bf16(a1, b, acc1, 0, 0, 0);
        }
        #pragma unroll
        for (int r = 0; r < 4; ++r) {
            zbuf[lm][wave * 16 + lq * 4 + r]       = acc0[r];
            zbuf[lm][(wave + 4) * 16 + lq * 4 + r] = acc1[r];
        }
        __syncthreads();

        // fused MI gates: 512 items = 128 rows x 4 u-cols
        #pragma unroll
        for (int e = 0; e < 2; ++e) {
            int row = xrow[e], j = xj[e];
            float z[4];
            #pragma unroll
            for (int g = 0; g < 4; ++g) {
                int l = g * 4 + j;
                float hp = zbuf[l][row] + brS[l];
                float xp = xpv[e][g];
                z[g] = alS[l] * xp * hp + b1S[l] * xp + b2S[l] * hp;
            }
            float cn = tanhf(z[2]) * sigmoidf_(z[0]) + cv[e] * sigmoidf_(z[1]);
            cv[e] = cn;
            hdst[gidx[e]] = f2bf(tanhf(cn) * sigmoidf_(z[3]));
        }

        // prefetch next step's XP BEFORE the barrier (XPc is constant within
        // the chunk, written by a prior kernel) so L3 latency overlaps the spin.
        if (s + 1 < tc) {
            #pragma unroll
            for (int e = 0; e < 2; ++e)
                #pragma unroll
                for (int g = 0; g < 4; ++g)
                    xpv[e][g] = bf2f(XPc[(size_t)(xrow[e] * tc + s + 1) * FOURU
                                         + ((g << 10) + u0 + xj[e])]);
        }

        // ---- device-scope barrier (one wbl2 + one inv per block per step) ----
        __syncthreads();   // all waves' h-stores vmcnt-drained
        if (tid == 0) {
            __builtin_amdgcn_fence(__ATOMIC_RELEASE, "agent");   // wbl2, waited
            unsigned old = __hip_atomic_fetch_add(&bar[sgrp], 1u,
                               __ATOMIC_RELAXED, __HIP_MEMORY_SCOPE_AGENT);
            if (old == 32u * (unsigned)(t + 1) - 1u)
                __hip_atomic_fetch_add(&bar[256], 1u,
                    __ATOMIC_RELAXED, __HIP_MEMORY_SCOPE_AGENT);
            while (__hip_atomic_load(&bar[256],
                       __ATOMIC_RELAXED, __HIP_MEMORY_SCOPE_AGENT)
                   < 8u * (unsigned)(t + 1))
                __builtin_amdgcn_s_sleep(2);
            __builtin_amdgcn_fence(__ATOMIC_ACQUIRE, "agent");   // inv
        }
        __syncthreads();
    }

    // write c-state back once per chunk
    #pragma unroll
    for (int e = 0; e < 2; ++e)
        cbuf[gidx[e]] = cv[e];
}

// ---------------------------------------------------------------- final GEMM
// out[128][1024] = h @ Wc + bc (fp32 out); WcT bf16 [1024][1024].
__global__ __launch_bounds__(256) void gemm_out(
    const u16* __restrict__ h, const u16* __restrict__ WcT,
    const float* __restrict__ bc, float* __restrict__ out)
{
    int tid = threadIdx.x;
    int wave = tid >> 6, lane = tid & 63;
    int bx = blockIdx.x;               // 128 blocks: 8 row-tiles x 16 col-grps
    int row0 = (bx & 7) * 16;
    int n0 = (bx >> 3) * 64 + wave * 16;
    int lm = lane & 15, lq = lane >> 4;

    f32x4 acc = {};
    const u16* Arow = &h[(size_t)(row0 + lm) * UNITS];
    const u16* Brow = &WcT[(size_t)(n0 + lm) * UNITS];
    #pragma unroll 8
    for (int k0 = 0; k0 < UNITS; k0 += 32) {
        short8 a = *(const short8*)&Arow[k0 + lq * 8];
        short8 b = *(const short8*)&Brow[k0 + lq * 8];
        acc = __builtin_amdgcn_mfma_f32_16x16x32_bf16(a, b, acc, 0, 0, 0);
    }
    int col = n0 + lm;
    float bv = bc[col];
    #pragma unroll
    for (int r = 0; r < 4; ++r) {
        int row = row0 + lq * 4 + r;
        out[(size_t)row * 1024 + col] = acc[r] + bv;
    }
}

// ---------------------------------------------------------------- utilities
__global__ void cvt_f32_bf16(const float* __restrict__ in, u16* __restrict__ out, int n) {
    int i = blockIdx.x * 256 + threadIdx.x;
    if (i < n) out[i] = f2bf(in[i]);
}
__global__ void cvt_bf16_f32(const u16* __restrict__ in, float* __restrict__ out, int n) {
    int i = blockIdx.x * 256 + threadIdx.x;
    if (i < n) out[i] = bf2f(in[i]);
}
__global__ void copy_f32(const float* __restrict__ in, float* __restrict__ out, int n) {
    int i = blockIdx.x * 256 + threadIdx.x;
    if (i < n) out[i] = in[i];
}
__global__ void zero_u32(unsigned* __restrict__ p, int n) {
    int i = blockIdx.x * 256 + threadIdx.x;
    if (i < n) p[i] = 0u;
}

// ---------------------------------------------------------------- launch
extern "C" void kernel_launch(void* const* d_in, const int* in_sizes, int n_in,
                              void* d_out, int out_size, void* d_ws, size_t ws_size,
                              hipStream_t stream)
{
    const float* x     = (const float*)d_in[0];   // [128,256,1024]
    const float* h0    = (const float*)d_in[1];   // [128,1024]
    const float* c0    = (const float*)d_in[2];   // [128,1024]
    const float* Wk    = (const float*)d_in[3];   // [1024,4096]
    const float* bk    = (const float*)d_in[4];   // [4096]
    const float* Wr    = (const float*)d_in[5];   // [1024,4096]
    const float* br    = (const float*)d_in[6];   // [4096]
    const float* alpha = (const float*)d_in[7];   // [1,4096]
    const float* beta1 = (const float*)d_in[8];   // [1,4096]
    const float* beta2 = (const float*)d_in[9];   // [1,4096]
    const float* Wc    = (const float*)d_in[10];  // [1024,1024]
    const float* bc    = (const float*)d_in[11];  // [1024]
    float* out = (float*)d_out;                   // out|h|c, each 128*1024 fp32

    // ws layout: small state, barrier counters, bf16 weights, then XP chunk
    char* p = (char*)d_ws;
    u16* h0bf = (u16*)p;  p += (size_t)B_SZ * UNITS * 2;
    u16* hb0  = (u16*)p;  p += (size_t)B_SZ * UNITS * 2;
    u16* hb1  = (u16*)p;  p += (size_t)B_SZ * UNITS * 2;
    float* cbuf = (float*)p; p += (size_t)B_SZ * UNITS * 4;
    unsigned* bar = (unsigned*)p; p += 2048;      // 8 subs (128B apart) + root
    u16* WkT = (u16*)p;   p += (size_t)FOURU * D_IN * 2;
    u16* WrT = (u16*)p;   p += (size_t)FOURU * UNITS * 2;
    u16* WcT = (u16*)p;   p += (size_t)1024 * 1024 * 2;
    u16* XPc = (u16*)p;   // bf16 [B_SZ*tc][4096]

    size_t fixedB = (size_t)(p - (char*)d_ws);
    int tc = 32, tcShift = 5;
    while (tc > 1 && fixedB + (size_t)B_SZ * tc * FOURU * 2 > ws_size) {
        tc >>= 1; tcShift -= 1;
    }

    // 1) weight transposes + fp32->bf16 convert
    transpose_cvt<<<dim3(FOURU / 32, D_IN / 32), 256, 0, stream>>>(Wk, WkT, D_IN, FOURU);
    transpose_cvt<<<dim3(FOURU / 32, UNITS / 32), 256, 0, stream>>>(Wr, WrT, UNITS, FOURU);
    transpose_cvt<<<dim3(1024 / 32, 1024 / 32), 256, 0, stream>>>(Wc, WcT, 1024, 1024);

    // 2) state init: h0 -> bf16, c0 -> fp32 scratch, barrier counters -> 0
    cvt_f32_bf16<<<(B_SZ * UNITS) / 256, 256, 0, stream>>>(h0, h0bf, B_SZ * UNITS);
    copy_f32<<<(B_SZ * UNITS) / 256, 256, 0, stream>>>(c0, cbuf, B_SZ * UNITS);
    zero_u32<<<2, 256, 0, stream>>>(bar, 512);

    // 3) recurrence: per chunk, XP GEMM then one persistent chunk kernel.
    //    Plain launch: 256 blocks, per-CU capacity >= 2 (LDS 42KB of 160KB,
    //    VGPR 68) => all blocks resident immediately; spin barrier is safe.
    for (int t0 = 0; t0 < T_SZ; t0 += tc) {
        gemm_xp_chunk<<<dim3(tc, FOURU / 128), 256, 0, stream>>>(
            x, WkT, bk, XPc, t0, tcShift);
        milstm_chunk<<<256, 256, 0, stream>>>(
            XPc, WrT, br, alpha, beta1, beta2, h0bf, hb0, hb1, cbuf, bar, t0, tc);
    }
    // T=256 even -> final h in hb1

    // 4) out = h @ Wc + bc ; emit h (bf16->f32), c (f32)
    gemm_out<<<128, 256, 0, stream>>>(hb1, WcT, bc, out);
    cvt_bf16_f32<<<(B_SZ * UNITS) / 256, 256, 0, stream>>>(hb1, out + B_SZ * UNITS, B_SZ * UNITS);
    copy_f32<<<(B_SZ * UNITS) / 256, 256, 0, stream>>>(cbuf, out + 2 * B_SZ * UNITS, B_SZ * UNITS);
}

// Round 4
// 2512.356 us; speedup vs baseline: 5.1515x; 1.9929x over previous
//
#include <hip/hip_runtime.h>

// MI-LSTM on MI355X (gfx950). I/O is FP32 (per reference dtypes); compute
// uses bf16 MFMA internally (test tolerance is bf16-grade: 1.156e-2).
// B=128, T=256, D_IN=1024, UNITS=1024, N_CLASS=1024.
//
// R9 = R8 with the barrier-counting deadlock fixed. R8 skipped the barrier on
// each chunk's last step but kept monotonic targets keyed to the global step
// index -> counters desynced by one barrier per chunk -> hang on chunk 1.
// Targets are now keyed to the number of barriers actually executed:
// barId = nbase + s + 1, nbase = (t0/tc)*(tc-1) from the host.
//
// Recurrence design (R8): h exchange uses agent-scope relaxed atomics
// (sc0/sc1 write-through stores + L2-bypass loads against the coherent
// memory-side L3) -> zero buffer_wbl2/buffer_inv (R7 paid ~15us/step in 64
// serialized L2 cache-ops per XCD per step). Grid = 4 INDEPENDENT row-groups
// of 32 batch rows; 64 blocks/group; block = 32 rows x 16 u-cols (64 n-cols);
// WrS 132KB in LDS for the whole chunk; 4 waves split (m-tile x K-half), each
// h row loaded once per block (16 MB/step from L3). Per-group 64-block
// barrier: two-level relaxed far-atomics, no fences. c-state in registers.

typedef unsigned short u16;
typedef __attribute__((ext_vector_type(8))) short short8;   // 8 x bf16 (4 VGPRs)
typedef __attribute__((ext_vector_type(4))) float f32x4;    // MFMA accumulator

#define B_SZ   128
#define T_SZ   256
#define D_IN   1024
#define UNITS  1024
#define FOURU  4096

__device__ __forceinline__ float bf2f(u16 h) {
    return __uint_as_float(((unsigned int)h) << 16);
}
__device__ __forceinline__ u16 f2bf(float f) {
    unsigned int u = __float_as_uint(f);
    u += 0x7fffu + ((u >> 16) & 1u);   // round-to-nearest-even
    return (u16)(u >> 16);
}
__device__ __forceinline__ float sigmoidf_(float x) {
    return 1.0f / (1.0f + __expf(-x));
}

// ---------------------------------------------------------------- transpose+cvt
// out[n][k] = bf16(in[k][n]);  in is fp32 [K][N] row-major.
__global__ __launch_bounds__(256) void transpose_cvt(
    const float* __restrict__ in, u16* __restrict__ out, int K, int N)
{
    __shared__ u16 t[32][33];
    int n0 = blockIdx.x * 32, k0 = blockIdx.y * 32;
    int c = threadIdx.x & 31, r = threadIdx.x >> 5;   // r in 0..7
    #pragma unroll
    for (int i = 0; i < 4; ++i) {
        int kk = r + i * 8;
        t[kk][c] = f2bf(in[(size_t)(k0 + kk) * N + n0 + c]);
    }
    __syncthreads();
    #pragma unroll
    for (int i = 0; i < 4; ++i) {
        int nn = r + i * 8;
        out[(size_t)(n0 + nn) * K + k0 + c] = t[c][nn];
    }
}

// ---------------------------------------------------------------- XP GEMM (one time-chunk)
// Cc[b*tc+tt][n] = bf16( x[b][t0+tt][:] @ Wk + bk ),  tt in [0,tc).
__global__ __launch_bounds__(256) void gemm_xp_chunk(
    const float* __restrict__ X, const u16* __restrict__ Bt,
    const float* __restrict__ bias, u16* __restrict__ Cc,
    int t0, int tcShift)
{
    __shared__ __align__(16) u16 As[128 * 40];
    __shared__ __align__(16) u16 Bs[128 * 40];
    int tid = threadIdx.x;
    int wave = tid >> 6, lane = tid & 63;
    int bm = blockIdx.x * 128;     // row' base, row' = b*tc + tt
    int bn = blockIdx.y * 128;
    int wm = (wave & 1) * 64, wn = (wave >> 1) * 64;
    int lm = lane & 15, lq = lane >> 4;
    int tcMask = (1 << tcShift) - 1;

    f32x4 acc[4][4] = {};

    for (int k0 = 0; k0 < D_IN; k0 += 32) {
        #pragma unroll
        for (int i = 0; i < 2; ++i) {
            int idx = tid + i * 256;
            int r = idx >> 2, q = idx & 3;
            int rowp = bm + r;
            int b = rowp >> tcShift;
            int tt = rowp & tcMask;
            const float* xs = &X[(size_t)(b * T_SZ + t0 + tt) * D_IN + k0 + q * 8];
            float4 f0 = *(const float4*)xs;
            float4 f1 = *(const float4*)(xs + 4);
            uint4 v;
            v.x = (unsigned)f2bf(f0.x) | ((unsigned)f2bf(f0.y) << 16);
            v.y = (unsigned)f2bf(f0.z) | ((unsigned)f2bf(f0.w) << 16);
            v.z = (unsigned)f2bf(f1.x) | ((unsigned)f2bf(f1.y) << 16);
            v.w = (unsigned)f2bf(f1.z) | ((unsigned)f2bf(f1.w) << 16);
            *(uint4*)&As[r * 40 + q * 8] = v;
            *(uint4*)&Bs[r * 40 + q * 8] =
                *(const uint4*)&Bt[(size_t)(bn + r) * D_IN + k0 + q * 8];
        }
        __syncthreads();
        short8 af[4], bf[4];
        #pragma unroll
        for (int t = 0; t < 4; ++t) {
            af[t] = *(const short8*)&As[(wm + t * 16 + lm) * 40 + lq * 8];
            bf[t] = *(const short8*)&Bs[(wn + t * 16 + lm) * 40 + lq * 8];
        }
        #pragma unroll
        for (int mt = 0; mt < 4; ++mt)
            #pragma unroll
            for (int nt = 0; nt < 4; ++nt)
                acc[mt][nt] = __builtin_amdgcn_mfma_f32_16x16x32_bf16(
                    af[mt], bf[nt], acc[mt][nt], 0, 0, 0);
        __syncthreads();
    }

    #pragma unroll
    for (int mt = 0; mt < 4; ++mt) {
        #pragma unroll
        for (int nt = 0; nt < 4; ++nt) {
            int col = bn + wn + nt * 16 + lm;
            float bv = bias[col];
            #pragma unroll
            for (int r = 0; r < 4; ++r) {
                int rowp = bm + wm + mt * 16 + lq * 4 + r;
                Cc[(size_t)rowp * FOURU + col] = f2bf(acc[mt][nt][r] + bv);
            }
        }
    }
}

// ---------------------------------------------------------------- persistent LSTM chunk (R9)
// 256 blocks x 256 threads. Group = blockIdx>>6 (4 groups x 32 batch rows,
// fully independent). Within group: u0 = (blockIdx&63)*16 -> block owns
// 32 rows x 16 u-cols (= 64 n-cols across the 4 gates).
// Waves: mw = wave&1 (m-tile), kh = wave>>1 (K-half); partial sums reduced
// through zbuf. WrS (64 n-rows x 1024 k bf16, 132KB) staged once per chunk.
// All h loads/stores are agent-scope relaxed atomics (sc0/sc1 -> coherent at
// L3, no fences needed). Barrier per group: 4 sub-counters x 16 + root,
// relaxed far-atomics, leader spin; targets keyed to executed-barrier count
// (nbase + s + 1), NOT the global step index (R8's deadlock).
__global__ __launch_bounds__(256) void milstm_chunk(
    const u16* __restrict__ XPc,     // bf16 [128*tc][4096], rowp = b*tc + s
    const u16* __restrict__ WrT,     // [4096][1024] bf16
    const float* __restrict__ br,
    const float* __restrict__ alpha,
    const float* __restrict__ beta1,
    const float* __restrict__ beta2,
    const u16* __restrict__ h0bf,    // [128][1024] bf16 (initial state)
    u16* __restrict__ hb0,
    u16* __restrict__ hb1,
    float* __restrict__ cbuf,        // [128][1024] f32 (chunk in/out of c-state)
    unsigned* __restrict__ bar,      // barrier counters (zeroed at t=0)
    int t0, int tc, int nbase)       // nbase = barriers executed before chunk
{
    __shared__ __align__(16) u16 WrS[64 * 1032];   // 132 KB, +8 pad per row
    __shared__ float zbuf[2][64][34];              // [khalf][n-local][m] partials
    __shared__ float brS[64], alS[64], b1S[64], b2S[64];

    int tid = threadIdx.x;
    int wave = tid >> 6, lane = tid & 63;
    int lm = lane & 15, lq = lane >> 4;
    int mw = wave & 1, kh = wave >> 1;
    int bid = blockIdx.x;
    int grp = bid >> 6, grp0 = grp * 32;
    int u0 = (bid & 63) * 16;
    unsigned grpBase = (unsigned)grp * 256u;       // u32 units; 1KB per group
    unsigned sub = ((unsigned)(bid & 63)) >> 4;    // 4 subs x 16 blocks

    // stage WrT slice once per chunk: 64 rows x 1024 bf16 = 8192 uint4
    for (int i = 0; i < 32; ++i) {
        int idx = i * 256 + tid;
        int l = idx >> 7, q = idx & 127;
        int n = ((l >> 4) << 10) + u0 + (l & 15);
        *(uint4*)&WrS[l * 1032 + q * 8] = *(const uint4*)&WrT[(size_t)n * 1024 + q * 8];
    }
    if (tid < 64) {
        int n = ((tid >> 4) << 10) + u0 + (tid & 15);
        brS[tid] = br[n]; alS[tid] = alpha[n];
        b1S[tid] = beta1[n]; b2S[tid] = beta2[n];
    }

    // epilogue cell ownership: row rl = tid>>3 (0..31), u-cols j0, j0+1
    int rl = tid >> 3, j0 = (tid & 7) * 2;
    int bg = grp0 + rl;                            // global batch row
    size_t cix = (size_t)bg * UNITS + u0 + j0;
    float cvl[2];
    { float2 c2 = *(const float2*)&cbuf[cix]; cvl[0] = c2.x; cvl[1] = c2.y; }
    __syncthreads();

    // XP prefetch for s=0: per gate, 2 adjacent bf16 as one u32
    unsigned xpq[4];
    {
        const u16* xb = XPc + (size_t)(bg * tc) * FOURU + u0 + j0;
        #pragma unroll
        for (int g = 0; g < 4; ++g) xpq[g] = *(const unsigned*)(xb + (g << 10));
    }

    for (int s = 0; s < tc; ++s) {
        int t = t0 + s;
        const u16* hsrc = (t == 0) ? h0bf : ((t & 1) ? hb0 : hb1);
        u16* hdst = (t & 1) ? hb1 : hb0;

        // ---- A burst: this wave's 16 rows x 512 k (K-half) as 32 u64
        // agent-scope relaxed loads (sc0/sc1: bypass L2, read coherent L3).
        // Hoisted so all 32 issue back-to-back and pipeline the L3 latency.
        unsigned long long* Ap = (unsigned long long*)
            &hsrc[(size_t)(grp0 + mw * 16 + lm) * UNITS + kh * 512 + lq * 8];
        unsigned long long aq[32];
        #pragma unroll
        for (int i = 0; i < 16; ++i) {
            aq[2 * i]     = __hip_atomic_load(Ap + i * 8,     __ATOMIC_RELAXED, __HIP_MEMORY_SCOPE_AGENT);
            aq[2 * i + 1] = __hip_atomic_load(Ap + i * 8 + 1, __ATOMIC_RELAXED, __HIP_MEMORY_SCOPE_AGENT);
        }

        const u16* Bl = &WrS[kh * 512 + lq * 8];
        f32x4 acc0 = {}, acc1 = {}, acc2 = {}, acc3 = {};
        #pragma unroll
        for (int i = 0; i < 16; ++i) {
            int k0 = i * 32;
            union { unsigned long long q[2]; short8 v; } a;
            a.q[0] = aq[2 * i]; a.q[1] = aq[2 * i + 1];
            short8 b0 = *(const short8*)&Bl[(0 * 16 + lm) * 1032 + k0];
            short8 b1 = *(const short8*)&Bl[(1 * 16 + lm) * 1032 + k0];
            short8 b2 = *(const short8*)&Bl[(2 * 16 + lm) * 1032 + k0];
            short8 b3 = *(const short8*)&Bl[(3 * 16 + lm) * 1032 + k0];
            acc0 = __builtin_amdgcn_mfma_f32_16x16x32_bf16(a.v, b0, acc0, 0, 0, 0);
            acc1 = __builtin_amdgcn_mfma_f32_16x16x32_bf16(a.v, b1, acc1, 0, 0, 0);
            acc2 = __builtin_amdgcn_mfma_f32_16x16x32_bf16(a.v, b2, acc2, 0, 0, 0);
            acc3 = __builtin_amdgcn_mfma_f32_16x16x32_bf16(a.v, b3, acc3, 0, 0, 0);
        }
        #pragma unroll
        for (int r = 0; r < 4; ++r) {
            int mrow = mw * 16 + lq * 4 + r;
            zbuf[kh][0 * 16 + lm][mrow] = acc0[r];
            zbuf[kh][1 * 16 + lm][mrow] = acc1[r];
            zbuf[kh][2 * 16 + lm][mrow] = acc2[r];
            zbuf[kh][3 * 16 + lm][mrow] = acc3[r];
        }
        __syncthreads();

        // ---- fused MI gates: 2 cells per thread (row rl, u-cols j0, j0+1)
        float hnew[2];
        #pragma unroll
        for (int jj = 0; jj < 2; ++jj) {
            float zz[4];
            #pragma unroll
            for (int g = 0; g < 4; ++g) {
                int l = g * 16 + j0 + jj;
                float hp = zbuf[0][l][rl] + zbuf[1][l][rl] + brS[l];
                float xp = bf2f((u16)(jj ? (xpq[g] >> 16) : (xpq[g] & 0xffffu)));
                zz[g] = alS[l] * xp * hp + b1S[l] * xp + b2S[l] * hp;
            }
            float cn = tanhf(zz[2]) * sigmoidf_(zz[0]) + cvl[jj] * sigmoidf_(zz[1]);
            cvl[jj] = cn;
            hnew[jj] = tanhf(cn) * sigmoidf_(zz[3]);
        }
        unsigned pk = (unsigned)f2bf(hnew[0]) | ((unsigned)f2bf(hnew[1]) << 16);
        // write-through store (sc0/sc1): lands at coherent L3, no dirty L2
        __hip_atomic_store((unsigned*)&hdst[cix], pk,
                           __ATOMIC_RELAXED, __HIP_MEMORY_SCOPE_AGENT);

        if (s + 1 < tc) {
            // prefetch next step's XP (plain loads; XPc constant within chunk)
            {
                const u16* xb = XPc + (size_t)(bg * tc + s + 1) * FOURU + u0 + j0;
                #pragma unroll
                for (int g = 0; g < 4; ++g) xpq[g] = *(const unsigned*)(xb + (g << 10));
            }
            // ---- per-group barrier, zero cache maintenance.
            // syncthreads drains each wave's vmcnt -> all sc1 h-stores are
            // at the coherence point before the leader arrives.
            // barId counts barriers actually executed (tc-1 per chunk).
            unsigned barId = (unsigned)(nbase + s + 1);
            __syncthreads();
            if (tid == 0) {
                unsigned old = __hip_atomic_fetch_add(&bar[grpBase + sub * 32u], 1u,
                                   __ATOMIC_RELAXED, __HIP_MEMORY_SCOPE_AGENT);
                if (old == 16u * barId - 1u)
                    __hip_atomic_fetch_add(&bar[grpBase + 128u], 1u,
                        __ATOMIC_RELAXED, __HIP_MEMORY_SCOPE_AGENT);
                while (__hip_atomic_load(&bar[grpBase + 128u],
                           __ATOMIC_RELAXED, __HIP_MEMORY_SCOPE_AGENT)
                       < 4u * barId)
                    __builtin_amdgcn_s_sleep(2);
            }
            __syncthreads();
        }
    }

    // write c-state back once per chunk (plain; kernel-end release flushes)
    { float2 c2; c2.x = cvl[0]; c2.y = cvl[1]; *(float2*)&cbuf[cix] = c2; }
}

// ---------------------------------------------------------------- final GEMM
// out[128][1024] = h @ Wc + bc (fp32 out); WcT bf16 [1024][1024].
__global__ __launch_bounds__(256) void gemm_out(
    const u16* __restrict__ h, const u16* __restrict__ WcT,
    const float* __restrict__ bc, float* __restrict__ out)
{
    int tid = threadIdx.x;
    int wave = tid >> 6, lane = tid & 63;
    int bx = blockIdx.x;               // 128 blocks: 8 row-tiles x 16 col-grps
    int row0 = (bx & 7) * 16;
    int n0 = (bx >> 3) * 64 + wave * 16;
    int lm = lane & 15, lq = lane >> 4;

    f32x4 acc = {};
    const u16* Arow = &h[(size_t)(row0 + lm) * UNITS];
    const u16* Brow = &WcT[(size_t)(n0 + lm) * UNITS];
    #pragma unroll 8
    for (int k0 = 0; k0 < UNITS; k0 += 32) {
        short8 a = *(const short8*)&Arow[k0 + lq * 8];
        short8 b = *(const short8*)&Brow[k0 + lq * 8];
        acc = __builtin_amdgcn_mfma_f32_16x16x32_bf16(a, b, acc, 0, 0, 0);
    }
    int col = n0 + lm;
    float bv = bc[col];
    #pragma unroll
    for (int r = 0; r < 4; ++r) {
        int row = row0 + lq * 4 + r;
        out[(size_t)row * 1024 + col] = acc[r] + bv;
    }
}

// ---------------------------------------------------------------- utilities
__global__ void cvt_f32_bf16(const float* __restrict__ in, u16* __restrict__ out, int n) {
    int i = blockIdx.x * 256 + threadIdx.x;
    if (i < n) out[i] = f2bf(in[i]);
}
__global__ void cvt_bf16_f32(const u16* __restrict__ in, float* __restrict__ out, int n) {
    int i = blockIdx.x * 256 + threadIdx.x;
    if (i < n) out[i] = bf2f(in[i]);
}
__global__ void copy_f32(const float* __restrict__ in, float* __restrict__ out, int n) {
    int i = blockIdx.x * 256 + threadIdx.x;
    if (i < n) out[i] = in[i];
}
__global__ void zero_u32(unsigned* __restrict__ p, int n) {
    int i = blockIdx.x * 256 + threadIdx.x;
    if (i < n) p[i] = 0u;
}

// ---------------------------------------------------------------- launch
extern "C" void kernel_launch(void* const* d_in, const int* in_sizes, int n_in,
                              void* d_out, int out_size, void* d_ws, size_t ws_size,
                              hipStream_t stream)
{
    const float* x     = (const float*)d_in[0];   // [128,256,1024]
    const float* h0    = (const float*)d_in[1];   // [128,1024]
    const float* c0    = (const float*)d_in[2];   // [128,1024]
    const float* Wk    = (const float*)d_in[3];   // [1024,4096]
    const float* bk    = (const float*)d_in[4];   // [4096]
    const float* Wr    = (const float*)d_in[5];   // [1024,4096]
    const float* br    = (const float*)d_in[6];   // [4096]
    const float* alpha = (const float*)d_in[7];   // [1,4096]
    const float* beta1 = (const float*)d_in[8];   // [1,4096]
    const float* beta2 = (const float*)d_in[9];   // [1,4096]
    const float* Wc    = (const float*)d_in[10];  // [1024,1024]
    const float* bc    = (const float*)d_in[11];  // [1024]
    float* out = (float*)d_out;                   // out|h|c, each 128*1024 fp32

    // ws layout: small state, barrier counters, bf16 weights, then XP chunk
    char* p = (char*)d_ws;
    u16* h0bf = (u16*)p;  p += (size_t)B_SZ * UNITS * 2;
    u16* hb0  = (u16*)p;  p += (size_t)B_SZ * UNITS * 2;
    u16* hb1  = (u16*)p;  p += (size_t)B_SZ * UNITS * 2;
    float* cbuf = (float*)p; p += (size_t)B_SZ * UNITS * 4;
    unsigned* bar = (unsigned*)p; p += 4096;      // 4 groups x 1KB counter region
    u16* WkT = (u16*)p;   p += (size_t)FOURU * D_IN * 2;
    u16* WrT = (u16*)p;   p += (size_t)FOURU * UNITS * 2;
    u16* WcT = (u16*)p;   p += (size_t)1024 * 1024 * 2;
    u16* XPc = (u16*)p;   // bf16 [B_SZ*tc][4096]

    size_t fixedB = (size_t)(p - (char*)d_ws);
    int tc = 32, tcShift = 5;
    while (tc > 1 && fixedB + (size_t)B_SZ * tc * FOURU * 2 > ws_size) {
        tc >>= 1; tcShift -= 1;
    }

    // 1) weight transposes + fp32->bf16 convert
    transpose_cvt<<<dim3(FOURU / 32, D_IN / 32), 256, 0, stream>>>(Wk, WkT, D_IN, FOURU);
    transpose_cvt<<<dim3(FOURU / 32, UNITS / 32), 256, 0, stream>>>(Wr, WrT, UNITS, FOURU);
    transpose_cvt<<<dim3(1024 / 32, 1024 / 32), 256, 0, stream>>>(Wc, WcT, 1024, 1024);

    // 2) state init: h0 -> bf16, c0 -> fp32 scratch, barrier counters -> 0
    cvt_f32_bf16<<<(B_SZ * UNITS) / 256, 256, 0, stream>>>(h0, h0bf, B_SZ * UNITS);
    copy_f32<<<(B_SZ * UNITS) / 256, 256, 0, stream>>>(c0, cbuf, B_SZ * UNITS);
    zero_u32<<<4, 256, 0, stream>>>(bar, 1024);

    // 3) recurrence: per chunk, XP GEMM then one persistent chunk kernel.
    //    256 blocks x 256 thr, ~150KB LDS -> strictly 1 block/CU, all resident.
    for (int t0 = 0; t0 < T_SZ; t0 += tc) {
        gemm_xp_chunk<<<dim3(tc, FOURU / 128), 256, 0, stream>>>(
            x, WkT, bk, XPc, t0, tcShift);
        int nbase = (t0 / tc) * (tc - 1);   // barriers executed before chunk
        milstm_chunk<<<256, 256, 0, stream>>>(
            XPc, WrT, br, alpha, beta1, beta2, h0bf, hb0, hb1, cbuf, bar,
            t0, tc, nbase);
    }
    // T=256 even -> final h in hb1

    // 4) out = h @ Wc + bc ; emit h (bf16->f32), c (f32)
    gemm_out<<<128, 256, 0, stream>>>(hb1, WcT, bc, out);
    cvt_bf16_f32<<<(B_SZ * UNITS) / 256, 256, 0, stream>>>(hb1, out + B_SZ * UNITS, B_SZ * UNITS);
    copy_f32<<<(B_SZ * UNITS) / 256, 256, 0, stream>>>(cbuf, out + 2 * B_SZ * UNITS, B_SZ * UNITS);
}